// Round 9
// baseline (297.014 us; speedup 1.0000x reference)
//
#include <hip/hip_runtime.h>
#include <hip/hip_bf16.h>

#define DEVI __device__ __forceinline__

constexpr int Bc = 2, Cc = 64, Tc = 4, Hc = 64, Wc = 64, OFFc = 54, KVc = 27;
constexpr int HW  = Hc * Wc;     // 4096
constexpr int THW = Tc * HW;     // 16384

typedef __attribute__((ext_vector_type(8))) short bf16x8;
typedef __attribute__((ext_vector_type(4))) float f32x4;

DEVI short f2bf(float f) {
    __hip_bfloat16 h = __float2bfloat16(f);
    return *reinterpret_cast<short*>(&h);
}
DEVI float bf2f(short s) {
    unsigned u = ((unsigned)(unsigned short)s) << 16;
    float f; __builtin_memcpy(&f, &u, 4); return f;
}

// ------- weights -> K-major MFMA A layout -------
// wAk[((tap*2+ch)*4+mf)*512 + l15*32 + q] = w[o=mf*16+l15][c=ch*32+q][tap]
__global__ __launch_bounds__(256) void w_prep(const float* __restrict__ w,
                                              __hip_bfloat16* __restrict__ wAk, int ovalid) {
    int i = blockIdx.x * 256 + threadIdx.x;   // 216*512 = 110592
    if (i >= 216 * 512) return;
    int u = i >> 9, r = i & 511;
    int mf = u & 3, ch = (u >> 2) & 1, tap = u >> 3;
    int o = mf * 16 + (r >> 5), c = ch * 32 + (r & 31);
    float v = (o < ovalid) ? w[(o * Cc + c) * KVc + tap] : 0.f;
    wAk[i] = __float2bfloat16(v);
}

// ------- cast + transpose to channel-last bf16: x[b][c][t][h][w] -> xcl[b][t][h][w][c] -------
__global__ __launch_bounds__(256) void cast_cl(const float* __restrict__ x,
                                               __hip_bfloat16* __restrict__ xcl) {
    __shared__ float s[64][65];
    int tid = threadIdx.x;
    int bi  = blockIdx.x;
    int h = bi & 63, t = (bi >> 6) & 3, b = bi >> 8;

    const float* xp = x + (size_t)b * Cc * THW + t * HW + h * 64;
    int w0 = tid & 63, c0 = tid >> 6;
    #pragma unroll
    for (int i = 0; i < 16; ++i) {
        int c = c0 + i * 4;
        s[c][w0] = xp[(size_t)c * THW + w0];
    }
    __syncthreads();

    __hip_bfloat16* dst = xcl + (((size_t)b * Tc + t) * HW + (size_t)h * 64) * 64;
    #pragma unroll
    for (int r = 0; r < 2; ++r) {
        int j  = tid + r * 256;
        int w  = j >> 3;
        int c8 = j & 7;
        bf16x8 v;
        #pragma unroll
        for (int jj = 0; jj < 8; ++jj)
            v[jj] = f2bf(s[c8 * 8 + jj][w]);
        *reinterpret_cast<bf16x8*>(dst + w * 64 + c8 * 8) = v;
    }
}

// ================= fused offset-conv + deformable-conv =================
// block = (b,t,h,quarter-row): 16 positions. 4 waves = tap-half (wv&1) x
// channel-half (wv>>1) K-split. Register-lean single-buffered inner loops;
// latency hidden by TLP: 2048 blocks = 8 blocks/CU, 6 waves/SIMD resident.
// XCD swizzle: plane (b,t) = blockIdx&7 => each XCD serves one ~2MB plane slab
// from its own L2 (R7-validated).
template <bool L2>
__global__ __launch_bounds__(256, 6) void fused_deform(
    const __hip_bfloat16* __restrict__ src, const __hip_bfloat16* __restrict__ owAk,
    const float* __restrict__ obias, const __hip_bfloat16* __restrict__ wAk,
    const float* __restrict__ xres, float* __restrict__ outf,
    __hip_bfloat16* __restrict__ ycl)
{
    __shared__ float s_off[KVc][2][18];
    __shared__ float s_red[16 * 68];

    int tid = threadIdx.x;
    int wv = tid >> 6, lane = tid & 63, l15 = lane & 15, l4 = lane >> 4;
    int th = wv & 1, chh = wv >> 1;
    int bi = blockIdx.x;
    int pid = bi & 7;                // (b,t) plane -> XCD via %8 round-robin
    int j   = bi >> 3;               // 0..255 within plane
    int q4 = j & 3, h = j >> 2;
    int b = pid >> 2, t = pid & 3;

    int p0 = q4 << 4;
    int p  = p0 + l15;               // global w position
    int cbase = chh * 32 + l4 * 8;   // channel slice of this wave

    // valid tap range (t-plane validity contiguous in tap), split between th waves
    int lo = (t == 0) ? 9 : 0;
    int hi = (t == 3) ? 18 : KVc;
    int mid = lo + ((hi - lo + 1) >> 1);
    int t0 = th ? mid : lo;
    int t1 = th ? hi : mid;

    // ---- phase 0: init s_off with bias, zero s_red ----
    for (int i = tid; i < KVc * 2 * 18; i += 256) {
        int k = i / 36, rem = i - k * 36, jj = rem / 18;
        s_off[0][0][i] = obias[2 * k + jj];   // pad entries junk; never read
    }
    for (int i = tid; i < 16 * 68; i += 256) s_red[i] = 0.f;
    __syncthreads();

    const __hip_bfloat16* xb = src + ((size_t)b << 20);

    // ---- phase 1: offset conv (per-wave tap sub-range, register-lean) ----
    {
        f32x4 cacc[4];
        #pragma unroll
        for (int mf = 0; mf < 4; ++mf) cacc[mf] = (f32x4){0.f, 0.f, 0.f, 0.f};

        for (int tap = t0; tap < t1; ++tap) {
            int kt = tap / 9, rr = tap - kt * 9, kh = rr / 3, kw = rr - kh * 3;
            int tt = t + kt - 1, hh = h + kh - 1;   // tt valid by range
            int ws = p + kw - 1;
            bf16x8 bv = {0, 0, 0, 0, 0, 0, 0, 0};
            if ((unsigned)hh < 64u && (unsigned)ws < 64u)
                bv = *reinterpret_cast<const bf16x8*>(xb + (((size_t)tt * HW + hh * 64 + ws) << 6) + cbase);
            const __hip_bfloat16* ab = owAk + ((tap * 2 + chh) << 11) + (l15 << 5) + (l4 << 3);
            #pragma unroll
            for (int mf = 0; mf < 4; ++mf) {
                bf16x8 af = *reinterpret_cast<const bf16x8*>(ab + (mf << 9));
                cacc[mf] = __builtin_amdgcn_mfma_f32_16x16x32_bf16(af, bv, cacc[mf], 0, 0, 0);
            }
        }
        #pragma unroll
        for (int mf = 0; mf < 4; ++mf)
            #pragma unroll
            for (int jj = 0; jj < 4; ++jj) {
                int o = mf * 16 + l4 * 4 + jj;
                if (o < OFFc) atomicAdd(&s_off[o >> 1][o & 1][l15], cacc[mf][jj]);
            }
    }
    __syncthreads();

    // ---- phase 2: deformable conv (per-wave tap sub-range, register-lean) ----
    f32x4 dacc[4];
    #pragma unroll
    for (int mf = 0; mf < 4; ++mf) dacc[mf] = (f32x4){0.f, 0.f, 0.f, 0.f};

    for (int tap = t0; tap < t1; ++tap) {
        int kt = tap / 9, rr = tap - kt * 9, kh = rr / 3, kw = rr - kh * 3;
        int tt = t + kt - 1;                       // valid by range
        const __hip_bfloat16* xt = xb + ((size_t)tt << 18);
        float dh = s_off[tap][0][l15], dw = s_off[tap][1][l15];
        float hs  = (float)(h + kh - 1) + dh;
        float wsf = (float)(p + kw - 1) + dw;
        float fh = floorf(hs), fw = floorf(wsf);
        int h0 = (int)fh, w0 = (int)fw, h1 = h0 + 1, w1 = w0 + 1;
        float lh = hs - fh, lw = wsf - fw;
        float u0 = (1.f - lh) * (((unsigned)h0 < 64u) ? 1.f : 0.f);
        float u1 = lh         * (((unsigned)h1 < 64u) ? 1.f : 0.f);
        float q0 = (1.f - lw) * (((unsigned)w0 < 64u) ? 1.f : 0.f);
        float q1 = lw         * (((unsigned)w1 < 64u) ? 1.f : 0.f);
        float c00 = u0 * q0, c01 = u0 * q1, c10 = u1 * q0, c11 = u1 * q1;
        int hc0 = min(max(h0, 0), 63), hc1 = min(max(h1, 0), 63);
        int wc0 = min(max(w0, 0), 63), wc1 = min(max(w1, 0), 63);
        bf16x8 g0 = *reinterpret_cast<const bf16x8*>(xt + ((hc0 * 64 + wc0) << 6) + cbase);
        bf16x8 g1 = *reinterpret_cast<const bf16x8*>(xt + ((hc0 * 64 + wc1) << 6) + cbase);
        bf16x8 g2 = *reinterpret_cast<const bf16x8*>(xt + ((hc1 * 64 + wc0) << 6) + cbase);
        bf16x8 g3 = *reinterpret_cast<const bf16x8*>(xt + ((hc1 * 64 + wc1) << 6) + cbase);
        bf16x8 bfrag;
        #pragma unroll
        for (int jj = 0; jj < 8; ++jj) {
            float s = c00 * bf2f(g0[jj]) + c01 * bf2f(g1[jj])
                    + c10 * bf2f(g2[jj]) + c11 * bf2f(g3[jj]);
            bfrag[jj] = f2bf(s);
        }
        const __hip_bfloat16* ab = wAk + ((tap * 2 + chh) << 11) + (l15 << 5) + (l4 << 3);
        #pragma unroll
        for (int mf = 0; mf < 4; ++mf) {
            bf16x8 af = *reinterpret_cast<const bf16x8*>(ab + (mf << 9));
            dacc[mf] = __builtin_amdgcn_mfma_f32_16x16x32_bf16(af, bfrag, dacc[mf], 0, 0, 0);
        }
    }

    #pragma unroll
    for (int mf = 0; mf < 4; ++mf)
        #pragma unroll
        for (int jj = 0; jj < 4; ++jj) {
            int o = mf * 16 + l4 * 4 + jj;
            atomicAdd(&s_red[l15 * 68 + o], dacc[mf][jj]);
        }
    __syncthreads();

    // ---- phase 3: fused epilogue ----
    if (!L2) {
        // leaky-relu + channel-last bf16 store (feeds layer-2 conv + sampling)
        if (tid < 128) {
            int pp = tid >> 3, o8 = (tid & 7) << 3;
            __hip_bfloat16* dst = ycl + ((((size_t)b * Tc + t) * HW + h * 64 + p0 + pp) << 6) + o8;
            bf16x8 o8v;
            #pragma unroll
            for (int jj = 0; jj < 8; ++jj) {
                float v = s_red[pp * 68 + o8 + jj];
                v = v >= 0.f ? v : 0.1f * v;
                o8v[jj] = f2bf(v);
            }
            *reinterpret_cast<bf16x8*>(dst) = o8v;
        }
    } else {
        // residual add + fp32 channel-first store
        int o = tid >> 2, pg = (tid & 3) << 2;
        size_t base = ((size_t)(b * Cc + o) * Tc + t) * HW + h * 64 + p0 + pg;
        f32x4 r, xv = *reinterpret_cast<const f32x4*>(xres + base);
        #pragma unroll
        for (int jj = 0; jj < 4; ++jj) r[jj] = s_red[(pg + jj) * 68 + o] + xv[jj];
        *reinterpret_cast<f32x4*>(outf + base) = r;
    }
}

extern "C" void kernel_launch(void* const* d_in, const int* in_sizes, int n_in,
                              void* d_out, int out_size, void* d_ws, size_t ws_size,
                              hipStream_t stream)
{
    const float* x   = (const float*)d_in[0];
    const float* w0  = (const float*)d_in[1];
    const float* ow0 = (const float*)d_in[2];
    const float* ob0 = (const float*)d_in[3];
    const float* w1  = (const float*)d_in[4];
    const float* ow1 = (const float*)d_in[5];
    const float* ob1 = (const float*)d_in[6];
    float* out = (float*)d_out;

    // ws layout (bf16): xcl 2M, ycl 2M, 4 weight buffers 110592 each => ~8.8 MB total
    __hip_bfloat16* xcl  = (__hip_bfloat16*)d_ws;
    __hip_bfloat16* ycl  = xcl  + (size_t)Bc * THW * 64;
    __hip_bfloat16* owA0 = ycl  + (size_t)Bc * THW * 64;
    __hip_bfloat16* owA1 = owA0 + (size_t)216 * 512;
    __hip_bfloat16* wA0  = owA1 + (size_t)216 * 512;
    __hip_bfloat16* wA1  = wA0  + (size_t)216 * 512;

    w_prep<<<432, 256, 0, stream>>>(ow0, owA0, OFFc);
    w_prep<<<432, 256, 0, stream>>>(ow1, owA1, OFFc);
    w_prep<<<432, 256, 0, stream>>>(w0,  wA0,  Cc);
    w_prep<<<432, 256, 0, stream>>>(w1,  wA1,  Cc);
    cast_cl<<<512, 256, 0, stream>>>(x, xcl);

    fused_deform<false><<<2048, 256, 0, stream>>>(xcl, owA0, ob0, wA0, nullptr, nullptr, ycl);
    fused_deform<true><<<2048, 256, 0, stream>>>(ycl, owA1, ob1, wA1, x, out, nullptr);
}

// Round 10
// 226.567 us; speedup vs baseline: 1.3109x; 1.3109x over previous
//
#include <hip/hip_runtime.h>
#include <hip/hip_bf16.h>

#define DEVI __device__ __forceinline__

constexpr int Bc = 2, Cc = 64, Tc = 4, Hc = 64, Wc = 64, OFFc = 54, KVc = 27;
constexpr int HW  = Hc * Wc;     // 4096
constexpr int THW = Tc * HW;     // 16384

typedef __attribute__((ext_vector_type(8))) short bf16x8;
typedef __attribute__((ext_vector_type(4))) float f32x4;

DEVI short f2bf(float f) {
    __hip_bfloat16 h = __float2bfloat16(f);
    return *reinterpret_cast<short*>(&h);
}
DEVI float bf2f(short s) {
    unsigned u = ((unsigned)(unsigned short)s) << 16;
    float f; __builtin_memcpy(&f, &u, 4); return f;
}

// ------- weights -> K-major MFMA A layout -------
// wAk[((tap*2+ch)*4+mf)*512 + l15*32 + q] = w[o=mf*16+l15][c=ch*32+q][tap]
__global__ __launch_bounds__(256) void w_prep(const float* __restrict__ w,
                                              __hip_bfloat16* __restrict__ wAk, int ovalid) {
    int i = blockIdx.x * 256 + threadIdx.x;   // 216*512 = 110592
    if (i >= 216 * 512) return;
    int u = i >> 9, r = i & 511;
    int mf = u & 3, ch = (u >> 2) & 1, tap = u >> 3;
    int o = mf * 16 + (r >> 5), c = ch * 32 + (r & 31);
    float v = (o < ovalid) ? w[(o * Cc + c) * KVc + tap] : 0.f;
    wAk[i] = __float2bfloat16(v);
}

// ------- cast + transpose to channel-last bf16: x[b][c][t][h][w] -> xcl[b][t][h][w][c] -------
__global__ __launch_bounds__(256) void cast_cl(const float* __restrict__ x,
                                               __hip_bfloat16* __restrict__ xcl) {
    __shared__ float s[64][65];
    int tid = threadIdx.x;
    int bi  = blockIdx.x;
    int h = bi & 63, t = (bi >> 6) & 3, b = bi >> 8;

    const float* xp = x + (size_t)b * Cc * THW + t * HW + h * 64;
    int w0 = tid & 63, c0 = tid >> 6;
    #pragma unroll
    for (int i = 0; i < 16; ++i) {
        int c = c0 + i * 4;
        s[c][w0] = xp[(size_t)c * THW + w0];
    }
    __syncthreads();

    __hip_bfloat16* dst = xcl + (((size_t)b * Tc + t) * HW + (size_t)h * 64) * 64;
    #pragma unroll
    for (int r = 0; r < 2; ++r) {
        int j  = tid + r * 256;
        int w  = j >> 3;
        int c8 = j & 7;
        bf16x8 v;
        #pragma unroll
        for (int jj = 0; jj < 8; ++jj)
            v[jj] = f2bf(s[c8 * 8 + jj][w]);
        *reinterpret_cast<bf16x8*>(dst + w * 64 + c8 * 8) = v;
    }
}

// ================= fused offset-conv + deformable-conv, LDS-staged =================
// block = (b,t,h) full row, 512 threads = 8 waves = nf(4 pos-groups) x chh(2 ch-halves).
// Per kt-plane: stage rows [h-2,h+2] (40KB, coalesced, XOR-swizzled) into LDS;
// all B-reads / bilinear corners become ds_read_b128. Pass A: offset conv -> s_off.
// Pass B: deform sampling -> dacc -> s_red (aliased on tile) -> fused epilogue.
// Global-gather fallback (wave-voted) keeps exactness for |dh|>=1 samples.
template <bool L2>
__global__ __launch_bounds__(512, 4) void fused_deform(
    const __hip_bfloat16* __restrict__ src, const __hip_bfloat16* __restrict__ owAk,
    const float* __restrict__ obias, const __hip_bfloat16* __restrict__ wAk,
    const float* __restrict__ xres, float* __restrict__ outf,
    __hip_bfloat16* __restrict__ ycl)
{
    __shared__ __align__(16) char s_mem[40960 + 14256];
    short* s_tile = (short*)s_mem;                 // [5][64 w][64 c] bf16, swizzled
    float* s_off  = (float*)(s_mem + 40960);       // [54][66]
    float* s_red  = (float*)s_mem;                 // aliased after pass B: [64][68]

    int tid = threadIdx.x;
    int wv = tid >> 6, lane = tid & 63, l15 = lane & 15, l4 = lane >> 4;
    int nf = wv & 3, chh = wv >> 2;
    int bi = blockIdx.x;
    int pid = bi & 7, h = bi >> 3;       // plane -> XCD via %8 round-robin
    int b = pid >> 2, t = pid & 3;
    int p = nf * 16 + l15;               // this lane's position (MFMA N index)
    int cbase = chh * 32 + l4 * 8;       // channel slice (MFMA K slice)
    int ktlo = (t == 0) ? 1 : 0, kthi = (t == 3) ? 2 : 3;

    // init s_off with bias
    for (int i = tid; i < OFFc * 66; i += 512) s_off[i] = obias[i / 66];

    const __hip_bfloat16* xb = src + ((size_t)b << 20);

    auto stage = [&](int kt) {
        int tt = t + kt - 1;   // valid by loop range
        const __hip_bfloat16* xt = xb + ((size_t)tt << 18);
        #pragma unroll
        for (int r = 0; r < 5; ++r) {
            int u = r * 512 + tid;            // 0..2559
            int sl = u >> 9, v = u & 511;
            int w = v >> 3, s = v & 7;
            int hh = h - 2 + sl;
            bf16x8 val = {0, 0, 0, 0, 0, 0, 0, 0};
            if ((unsigned)hh < 64u)
                val = *reinterpret_cast<const bf16x8*>(xt + ((hh * 64 + w) << 6) + s * 8);
            int byte = (sl * 8192 + w * 128 + s * 16) ^ ((w & 7) << 4);
            *reinterpret_cast<bf16x8*>((char*)s_tile + byte) = val;
        }
    };
    auto ldread = [&](int sl, int w) -> bf16x8 {
        int byte = (sl * 8192 + w * 128 + cbase * 2) ^ ((w & 7) << 4);
        return *reinterpret_cast<const bf16x8*>((const char*)s_tile + byte);
    };

    // ---- pass A: offset conv (B from LDS tile) ----
    f32x4 cacc[4];
    #pragma unroll
    for (int mf = 0; mf < 4; ++mf) cacc[mf] = (f32x4){0.f, 0.f, 0.f, 0.f};

    for (int kt = ktlo; kt < kthi; ++kt) {
        __syncthreads();
        stage(kt);
        __syncthreads();
        #pragma unroll
        for (int rr = 0; rr < 9; ++rr) {
            int kh = rr / 3, kw = rr % 3;
            int tap = kt * 9 + rr;
            int ws = p + kw - 1;
            int wsc = min(max(ws, 0), 63);
            bf16x8 bv = ldread(kh + 1, wsc);
            if ((unsigned)ws >= 64u) bv = (bf16x8){0, 0, 0, 0, 0, 0, 0, 0};
            const __hip_bfloat16* ab = owAk + ((tap * 2 + chh) << 11) + (l15 << 5) + (l4 << 3);
            #pragma unroll
            for (int mf = 0; mf < 4; ++mf) {
                bf16x8 af = *reinterpret_cast<const bf16x8*>(ab + (mf << 9));
                cacc[mf] = __builtin_amdgcn_mfma_f32_16x16x32_bf16(af, bv, cacc[mf], 0, 0, 0);
            }
        }
    }
    #pragma unroll
    for (int mf = 0; mf < 4; ++mf)
        #pragma unroll
        for (int jj = 0; jj < 4; ++jj) {
            int o = mf * 16 + l4 * 4 + jj;
            if (o < OFFc) atomicAdd(&s_off[o * 66 + p], cacc[mf][jj]);
        }

    // ---- pass B: deformable conv (corners from LDS tile) ----
    f32x4 dacc[4];
    #pragma unroll
    for (int mf = 0; mf < 4; ++mf) dacc[mf] = (f32x4){0.f, 0.f, 0.f, 0.f};

    for (int kt = ktlo; kt < kthi; ++kt) {
        __syncthreads();
        stage(kt);
        __syncthreads();
        int tt = t + kt - 1;
        const __hip_bfloat16* xt = xb + ((size_t)tt << 18);
        #pragma unroll
        for (int rr = 0; rr < 9; ++rr) {
            int kh = rr / 3, kw = rr % 3;
            int tap = kt * 9 + rr;
            float dh = s_off[(tap * 2 + 0) * 66 + p];
            float dw = s_off[(tap * 2 + 1) * 66 + p];
            float hs  = (float)(h + kh - 1) + dh;
            float wsf = (float)(p + kw - 1) + dw;
            float fh = floorf(hs), fw = floorf(wsf);
            int h0 = (int)fh, w0 = (int)fw;
            float lh = hs - fh, lw = wsf - fw;
            float q0 = (1.f - lw) * (((unsigned)w0 < 64u) ? 1.f : 0.f);
            float q1 = lw         * (((unsigned)(w0 + 1) < 64u) ? 1.f : 0.f);
            float c00, c01, c10, c11;
            int wc0 = min(max(w0, 0), 63), wc1 = min(max(w0 + 1, 0), 63);
            bf16x8 g0, g1, g2, g3;
            bool bad = (h0 < h - 2) | (h0 > h + 1);
            if (__any((int)bad)) {
                // exact global fallback (offsets >= 1 row; ~never taken)
                float u0 = (1.f - lh) * (((unsigned)h0 < 64u) ? 1.f : 0.f);
                float u1 = lh         * (((unsigned)(h0 + 1) < 64u) ? 1.f : 0.f);
                c00 = u0 * q0; c01 = u0 * q1; c10 = u1 * q0; c11 = u1 * q1;
                int hc0 = min(max(h0, 0), 63), hc1 = min(max(h0 + 1, 0), 63);
                g0 = *reinterpret_cast<const bf16x8*>(xt + ((hc0 * 64 + wc0) << 6) + cbase);
                g1 = *reinterpret_cast<const bf16x8*>(xt + ((hc0 * 64 + wc1) << 6) + cbase);
                g2 = *reinterpret_cast<const bf16x8*>(xt + ((hc1 * 64 + wc0) << 6) + cbase);
                g3 = *reinterpret_cast<const bf16x8*>(xt + ((hc1 * 64 + wc1) << 6) + cbase);
            } else {
                // LDS path: h-masks free (border rows zero-filled)
                c00 = (1.f - lh) * q0; c01 = (1.f - lh) * q1; c10 = lh * q0; c11 = lh * q1;
                int r0 = h0 - (h - 2);
                g0 = ldread(r0, wc0);     g1 = ldread(r0, wc1);
                g2 = ldread(r0 + 1, wc0); g3 = ldread(r0 + 1, wc1);
            }
            bf16x8 bfrag;
            #pragma unroll
            for (int jj = 0; jj < 8; ++jj) {
                float s = c00 * bf2f(g0[jj]) + c01 * bf2f(g1[jj])
                        + c10 * bf2f(g2[jj]) + c11 * bf2f(g3[jj]);
                bfrag[jj] = f2bf(s);
            }
            const __hip_bfloat16* ab = wAk + ((tap * 2 + chh) << 11) + (l15 << 5) + (l4 << 3);
            #pragma unroll
            for (int mf = 0; mf < 4; ++mf) {
                bf16x8 af = *reinterpret_cast<const bf16x8*>(ab + (mf << 9));
                dacc[mf] = __builtin_amdgcn_mfma_f32_16x16x32_bf16(af, bfrag, dacc[mf], 0, 0, 0);
            }
        }
    }

    // ---- reduce: s_red aliased onto tile (tile dead now) ----
    __syncthreads();
    for (int i = tid; i < 64 * 68; i += 512) s_red[i] = 0.f;
    __syncthreads();
    #pragma unroll
    for (int mf = 0; mf < 4; ++mf)
        #pragma unroll
        for (int jj = 0; jj < 4; ++jj) {
            int o = mf * 16 + l4 * 4 + jj;
            atomicAdd(&s_red[p * 68 + o], dacc[mf][jj]);
        }
    __syncthreads();

    // ---- fused epilogue ----
    if (!L2) {
        // leaky-relu + channel-last bf16 store (feeds layer-2 conv + sampling)
        int pp = tid >> 3, o8 = (tid & 7) << 3;
        __hip_bfloat16* dst = ycl + ((((size_t)b * Tc + t) * HW + h * 64 + pp) << 6) + o8;
        bf16x8 o8v;
        #pragma unroll
        for (int jj = 0; jj < 8; ++jj) {
            float v = s_red[pp * 68 + o8 + jj];
            v = v >= 0.f ? v : 0.1f * v;
            o8v[jj] = f2bf(v);
        }
        *reinterpret_cast<bf16x8*>(dst) = o8v;
    } else {
        // residual add + fp32 channel-first store
        int o = tid >> 3, pg = (tid & 7) << 3;
        size_t base = ((size_t)(b * Cc + o) * Tc + t) * HW + h * 64 + pg;
        #pragma unroll
        for (int q = 0; q < 2; ++q) {
            f32x4 r, xv = *reinterpret_cast<const f32x4*>(xres + base + q * 4);
            #pragma unroll
            for (int jj = 0; jj < 4; ++jj) r[jj] = s_red[(pg + q * 4 + jj) * 68 + o] + xv[jj];
            *reinterpret_cast<f32x4*>(outf + base + q * 4) = r;
        }
    }
}

extern "C" void kernel_launch(void* const* d_in, const int* in_sizes, int n_in,
                              void* d_out, int out_size, void* d_ws, size_t ws_size,
                              hipStream_t stream)
{
    const float* x   = (const float*)d_in[0];
    const float* w0  = (const float*)d_in[1];
    const float* ow0 = (const float*)d_in[2];
    const float* ob0 = (const float*)d_in[3];
    const float* w1  = (const float*)d_in[4];
    const float* ow1 = (const float*)d_in[5];
    const float* ob1 = (const float*)d_in[6];
    float* out = (float*)d_out;

    // ws layout (bf16): xcl 2M, ycl 2M, 4 weight buffers 110592 each => ~8.8 MB total
    __hip_bfloat16* xcl  = (__hip_bfloat16*)d_ws;
    __hip_bfloat16* ycl  = xcl  + (size_t)Bc * THW * 64;
    __hip_bfloat16* owA0 = ycl  + (size_t)Bc * THW * 64;
    __hip_bfloat16* owA1 = owA0 + (size_t)216 * 512;
    __hip_bfloat16* wA0  = owA1 + (size_t)216 * 512;
    __hip_bfloat16* wA1  = wA0  + (size_t)216 * 512;

    w_prep<<<432, 256, 0, stream>>>(ow0, owA0, OFFc);
    w_prep<<<432, 256, 0, stream>>>(ow1, owA1, OFFc);
    w_prep<<<432, 256, 0, stream>>>(w0,  wA0,  Cc);
    w_prep<<<432, 256, 0, stream>>>(w1,  wA1,  Cc);
    cast_cl<<<512, 256, 0, stream>>>(x, xcl);

    fused_deform<false><<<512, 512, 0, stream>>>(xcl, owA0, ob0, wA0, nullptr, nullptr, ycl);
    fused_deform<true><<<512, 512, 0, stream>>>(ycl, owA1, ob1, wA1, x, out, nullptr);
}